// Round 1
// baseline (261.874 us; speedup 1.0000x reference)
//
#include <hip/hip_runtime.h>
#include <hip/hip_bf16.h>
#include <cmath>

#define B_ 8
#define L_ 2048
#define D_ 256
#define BK 32
#define NITER (L_/BK)   // 64
#define KSTR 264        // 256 + 8 pad (row = 528 B = 33 16B-chunks, bank-uniform)
#define VSTR 40         // 32 + 8 pad  (row = 80 B = 5 chunks)
#define PSTR 40

typedef __attribute__((ext_vector_type(8))) short bf16x8;
typedef __attribute__((ext_vector_type(4))) float f32x4;

#define MFMA16(a,b,c) __builtin_amdgcn_mfma_f32_16x16x32_bf16((a),(b),(c),0,0,0)
#define NEG_INF (-__builtin_inff())

__device__ __forceinline__ f32x4 fmax4(f32x4 a, f32x4 b){
  f32x4 r;
  r[0]=fmaxf(a[0],b[0]); r[1]=fmaxf(a[1],b[1]);
  r[2]=fmaxf(a[2],b[2]); r[3]=fmaxf(a[3],b[3]);
  return r;
}

// ---------------- prepass: mask -> {0, -inf} floats ----------------
__global__ void prep_mask_k(const int* __restrict__ m, float* __restrict__ mf){
  int i = blockIdx.x*256 + threadIdx.x;
  mf[i] = m[i] ? NEG_INF : 0.0f;
}

// ---------------- prepass: x -> xh, xl (bf16 split), xt (= xh transposed) ----
__global__ void prep_conv_k(const float* __restrict__ x,
                            __hip_bfloat16* __restrict__ xh,
                            __hip_bfloat16* __restrict__ xl,
                            __hip_bfloat16* __restrict__ xt){
  __shared__ __hip_bfloat16 T[64][72];
  const int d0 = blockIdx.x*64, l0 = blockIdx.y*64, b = blockIdx.z;
  const int c = threadIdx.x & 63, r0 = threadIdx.x >> 6;
  #pragma unroll
  for (int i=0;i<16;i++){
    int r = r0 + i*4;
    size_t idx = ((size_t)(b*L_ + l0 + r))*D_ + d0 + c;
    float v = x[idx];
    __hip_bfloat16 h = __float2bfloat16(v);
    float hf = __bfloat162float(h);
    xh[idx] = h;
    xl[idx] = __float2bfloat16(v - hf);
    T[c][r] = h;            // transpose within tile: T[d][l]
  }
  __syncthreads();
  #pragma unroll
  for (int i=0;i<16;i++){
    int r = r0 + i*4;       // d within tile
    size_t idx = ((size_t)(b*D_ + d0 + r))*L_ + l0 + c;
    xt[idx] = T[r][c];
  }
}

// ---------------- flash attention ----------------
// grid (L/64, B), block 256 = 4 waves; wave owns 16 query rows.
__launch_bounds__(256, 1)
__global__ void flash_k(const __hip_bfloat16* __restrict__ xh,
                        const __hip_bfloat16* __restrict__ xl,
                        const __hip_bfloat16* __restrict__ xt,
                        const float* __restrict__ maskf,
                        float* __restrict__ out){
  // K-tile (hi/lo) row-major [BK][KSTR], V-tile transposed [D][VSTR], P per wave
  __shared__ __attribute__((aligned(16))) __hip_bfloat16 sKhi[BK*KSTR + 256]; // +512B tail pad (17th chunk-slot)
  __shared__ __attribute__((aligned(16))) __hip_bfloat16 sKlo[BK*KSTR + 256];
  __shared__ __attribute__((aligned(16))) __hip_bfloat16 sVt [D_*VSTR];       // 1280 chunks exactly
  __shared__ __attribute__((aligned(16))) __hip_bfloat16 sP  [4][16*PSTR];

  const int tid  = threadIdx.x;
  const int wave = tid >> 6, lane = tid & 63;
  const int quad = lane >> 4, l16 = lane & 15;
  const int b    = blockIdx.y;
  const int q0   = blockIdx.x * 64;
  const int q0w  = q0 + wave*16;

  // ---- Q fragments, register resident (A-layout: row = lane&15, k = quad*8+j) ----
  bf16x8 qh[8], ql[8];
  {
    const __hip_bfloat16* qr  = xh + ((size_t)(b*L_ + q0w + l16))*D_;
    const __hip_bfloat16* qrl = xl + ((size_t)(b*L_ + q0w + l16))*D_;
    #pragma unroll
    for (int ks=0; ks<8; ++ks){
      qh[ks] = *(const bf16x8*)(qr  + ks*32 + quad*8);
      ql[ks] = *(const bf16x8*)(qrl + ks*32 + quad*8);
    }
  }

  // ---- staging: per-lane static byte offsets for global_load_lds (16B chunks) ----
  // wave0: Khi (17 slots of 1056 chunks, rows of 33 chunks), wave1: Klo,
  // wave2: Vt slots 0..9, wave3: Vt slots 10..19 (rows of 5 chunks).
  unsigned goff[17];
  if (wave < 2){
    #pragma unroll
    for (int i=0;i<17;i++){
      int c = i*64 + lane;
      int row = c/33, cc = c - row*33;
      if (row > 31){ row = 31; cc = 0; }   // tail-pad chunks -> dummy
      if (cc >= 32) cc = 0;                // row-pad chunk -> dummy
      goff[i] = (unsigned)(row*512 + cc*16);
    }
  } else {
    #pragma unroll
    for (int i=0;i<10;i++){
      int c = (wave==2 ? i : i+10)*64 + lane;
      int d = c/5, cc = c - d*5;
      if (cc >= 4) cc = 0;                 // row-pad chunk -> dummy
      goff[i] = (unsigned)(d*(L_*2) + cc*16);
    }
  }
  const char* gsrc0; char* ldst0;
  if      (wave==0){ gsrc0=(const char*)(xh + (size_t)b*L_*D_); ldst0=(char*)sKhi; }
  else if (wave==1){ gsrc0=(const char*)(xl + (size_t)b*L_*D_); ldst0=(char*)sKlo; }
  else if (wave==2){ gsrc0=(const char*)(xt + (size_t)b*D_*L_); ldst0=(char*)sVt;  }
  else             { gsrc0=(const char*)(xt + (size_t)b*D_*L_); ldst0=(char*)sVt + 10240; }

  // ---- online softmax state (per lane: rows quad*4 + r) ----
  f32x4 O[16];
  #pragma unroll
  for (int i=0;i<16;i++) O[i] = (f32x4){0.f,0.f,0.f,0.f};
  f32x4 mold = (f32x4){NEG_INF,NEG_INF,NEG_INF,NEG_INF};
  f32x4 lsum = (f32x4){0.f,0.f,0.f,0.f};

  for (int it=0; it<NITER; ++it){
    const int k0 = it*BK;
    __syncthreads();   // previous tile fully consumed
    {
      const char* gb = gsrc0 + (wave<2 ? k0*512 : k0*2);
      if (wave < 2){
        #pragma unroll
        for (int i=0;i<17;i++)
          __builtin_amdgcn_global_load_lds(
            (const __attribute__((address_space(1))) void*)(gb + goff[i]),
            (__attribute__((address_space(3))) void*)(ldst0 + i*1024), 16, 0, 0);
      } else {
        #pragma unroll
        for (int i=0;i<10;i++)
          __builtin_amdgcn_global_load_lds(
            (const __attribute__((address_space(1))) void*)(gb + goff[i]),
            (__attribute__((address_space(3))) void*)(ldst0 + i*1024), 16, 0, 0);
      }
    }
    __syncthreads();   // staged tile visible (vmcnt drained by barrier)

    // ---- S = Q·Kt via bf16x3 (hh + hl + lh), 2 n-tiles of 16 keys ----
    f32x4 Shh[2], Shl[2], Slh[2];
    #pragma unroll
    for (int nt=0; nt<2; ++nt){
      Shh[nt]=(f32x4){0.f,0.f,0.f,0.f};
      Shl[nt]=(f32x4){0.f,0.f,0.f,0.f};
      Slh[nt]=(f32x4){0.f,0.f,0.f,0.f};
    }
    #pragma unroll
    for (int ks=0; ks<8; ++ks){
      #pragma unroll
      for (int nt=0; nt<2; ++nt){
        bf16x8 bh = *(const bf16x8*)(sKhi + (nt*16+l16)*KSTR + ks*32 + quad*8);
        bf16x8 bl = *(const bf16x8*)(sKlo + (nt*16+l16)*KSTR + ks*32 + quad*8);
        Shh[nt] = MFMA16(qh[ks], bh, Shh[nt]);
        Slh[nt] = MFMA16(ql[ks], bh, Slh[nt]);
        Shl[nt] = MFMA16(qh[ks], bl, Shl[nt]);
      }
    }

    // ---- combine, diagonal-zero, key padding mask ----
    f32x4 S[2];
    #pragma unroll
    for (int nt=0; nt<2; ++nt){
      S[nt] = Shh[nt] + Shl[nt] + Slh[nt];
      const int kg = k0 + nt*16 + l16;          // global key (C col = lane&15)
      const float mk = maskf[b*L_ + kg];        // 0 or -inf
      #pragma unroll
      for (int r=0;r<4;++r){
        if (kg == q0w + quad*4 + r) S[nt][r] = 0.0f;   // diag zero BEFORE mask
        S[nt][r] += mk;                                 // -inf dominates
      }
    }

    // ---- online softmax: row max over 16 lanes x 2 tiles ----
    f32x4 t = fmax4(S[0], S[1]);
    #pragma unroll
    for (int off=1; off<16; off<<=1){
      f32x4 o;
      o[0]=__shfl_xor(t[0],off); o[1]=__shfl_xor(t[1],off);
      o[2]=__shfl_xor(t[2],off); o[3]=__shfl_xor(t[3],off);
      t = fmax4(t,o);
    }
    f32x4 mnew = fmax4(mold, t);
    f32x4 mx, alpha;
    #pragma unroll
    for (int r=0;r<4;++r){
      mx[r]    = (mnew[r] > NEG_INF) ? mnew[r] : 0.0f;  // all-masked-tile guard
      alpha[r] = __expf(mold[r] - mx[r]);
    }
    f32x4 P[2];
    #pragma unroll
    for (int nt=0; nt<2; ++nt)
      #pragma unroll
      for (int r=0;r<4;++r)
        P[nt][r] = __expf(S[nt][r] - mx[r]);
    f32x4 rs = P[0] + P[1];
    #pragma unroll
    for (int off=1; off<16; off<<=1){
      f32x4 o;
      o[0]=__shfl_xor(rs[0],off); o[1]=__shfl_xor(rs[1],off);
      o[2]=__shfl_xor(rs[2],off); o[3]=__shfl_xor(rs[3],off);
      rs = rs + o;
    }
    #pragma unroll
    for (int r=0;r<4;++r) lsum[r] = lsum[r]*alpha[r] + rs[r];
    mold = mnew;
    #pragma unroll
    for (int vt=0; vt<16; ++vt) O[vt] *= alpha;

    // ---- P: C-layout -> LDS -> A-layout ----
    #pragma unroll
    for (int nt=0; nt<2; ++nt)
      #pragma unroll
      for (int r=0;r<4;++r)
        sP[wave][(quad*4+r)*PSTR + nt*16 + l16] = __float2bfloat16(P[nt][r]);
    __threadfence_block();   // order ds_write -> ds_read within wave
    bf16x8 pf = *(const bf16x8*)(&sP[wave][l16*PSTR + quad*8]);

    // ---- O += P · V  (B-frags from transposed V tile) ----
    #pragma unroll
    for (int vt=0; vt<16; ++vt){
      bf16x8 bv = *(const bf16x8*)(sVt + (vt*16+l16)*VSTR + quad*8);
      O[vt] = MFMA16(pf, bv, O[vt]);
    }
  }

  // ---- epilogue: normalize and store fp32 ----
  f32x4 inv;
  #pragma unroll
  for (int r=0;r<4;++r) inv[r] = 1.0f / lsum[r];
  #pragma unroll
  for (int vt=0; vt<16; ++vt)
    #pragma unroll
    for (int r=0;r<4;++r){
      size_t o = ((size_t)(b*L_ + q0w + quad*4 + r))*D_ + vt*16 + l16;
      out[o] = O[vt][r]*inv[r];
    }
}

extern "C" void kernel_launch(void* const* d_in, const int* in_sizes, int n_in,
                              void* d_out, int out_size, void* d_ws, size_t ws_size,
                              hipStream_t stream) {
  const float* x    = (const float*)d_in[0];
  const int*   mask = (const int*)d_in[1];
  float*       out  = (float*)d_out;

  const size_t NE = (size_t)B_*L_*D_;
  __hip_bfloat16* xh = (__hip_bfloat16*)d_ws;
  __hip_bfloat16* xl = xh + NE;
  __hip_bfloat16* xt = xl + NE;
  float*        maskf = (float*)(xt + NE);   // total ws use ~24.1 MB

  prep_mask_k<<<dim3((B_*L_)/256), dim3(256), 0, stream>>>(mask, maskf);
  prep_conv_k<<<dim3(D_/64, L_/64, B_), dim3(256), 0, stream>>>(x, xh, xl, xt);
  flash_k   <<<dim3(L_/64, B_), dim3(256), 0, stream>>>(xh, xl, xt, maskf, out);
}

// Round 2
// 233.510 us; speedup vs baseline: 1.1215x; 1.1215x over previous
//
#include <hip/hip_runtime.h>
#include <hip/hip_bf16.h>

#define B_ 8
#define L_ 2048
#define D_ 256
#define BK 32
#define KSPLIT 2
#define KHALF (L_/KSPLIT)      // 1024 keys per split
#define NIT (KHALF/BK)         // 32 iterations
#define KSTR 264               // fp16 elems per K row in LDS (528 B = 33 chunks)
#define VSTR 40                // 32 keys + 8 pad
#define PSTR 40
#define NROW (B_*L_)           // 16384

typedef __attribute__((ext_vector_type(8))) _Float16 f16x8;
typedef __attribute__((ext_vector_type(4))) float f32x4;

#define MFMA16F(a,b,c) __builtin_amdgcn_mfma_f32_16x16x32_f16((a),(b),(c),0,0,0)
#define NEG_INF (-__builtin_inff())

__device__ __forceinline__ f32x4 fmax4(f32x4 a, f32x4 b){
  f32x4 r;
  r[0]=fmaxf(a[0],b[0]); r[1]=fmaxf(a[1],b[1]);
  r[2]=fmaxf(a[2],b[2]); r[3]=fmaxf(a[3],b[3]);
  return r;
}

// ---------------- prep: fp32 x -> fp16 x16 (row-major) + xt16 (d-major) ----
__global__ void prep_k(const float* __restrict__ x,
                       _Float16* __restrict__ x16,
                       _Float16* __restrict__ xt16){
  __shared__ _Float16 T[64][66];   // [l][d], 66 = +2 pad (33-word rows: odd mod 32)
  const int t = threadIdx.x;
  const int d0 = blockIdx.x*64, l0 = blockIdx.y*64, b = blockIdx.z;
  const int lr = t>>3, c8 = (t&7)*8;
  #pragma unroll
  for (int p=0;p<2;++p){
    int l = lr + p*32;
    size_t idx = ((size_t)(b*L_ + l0 + l))*D_ + d0 + c8;
    float4 v0 = *(const float4*)(x + idx);
    float4 v1 = *(const float4*)(x + idx + 4);
    f16x8 h;
    h[0]=(_Float16)v0.x; h[1]=(_Float16)v0.y; h[2]=(_Float16)v0.z; h[3]=(_Float16)v0.w;
    h[4]=(_Float16)v1.x; h[5]=(_Float16)v1.y; h[6]=(_Float16)v1.z; h[7]=(_Float16)v1.w;
    *(f16x8*)(x16 + idx) = h;
    #pragma unroll
    for (int j=0;j<8;++j) T[l][c8+j] = h[j];   // scalar writes, ~2-way banks
  }
  __syncthreads();
  // write-out: 8 consecutive lanes cover 128B contiguous of one d-row (coalesced)
  const int dd = t>>3, l8 = (t&7)*8;
  #pragma unroll
  for (int p=0;p<2;++p){
    int d = dd + p*32;
    f16x8 a;
    #pragma unroll
    for (int j=0;j<8;++j) a[j] = T[l8+j][d];   // d-pairs share words -> broadcast
    size_t od = ((size_t)(b*D_ + d0 + d))*L_ + l0 + l8;
    *(f16x8*)(xt16 + od) = a;
  }
}

// ---------------- flash attention over one key-split ----------------
// grid (L/64, B, KSPLIT), block 256 = 4 waves; wave owns 16 query rows.
__launch_bounds__(256, 2)
__global__ void flash_k(const _Float16* __restrict__ x16,
                        const _Float16* __restrict__ xt16,
                        const int* __restrict__ mask,
                        float* __restrict__ out0,
                        float* __restrict__ out1,
                        float* __restrict__ mlm,
                        float* __restrict__ mll){
  __shared__ __attribute__((aligned(16))) _Float16 sK [17*512];  // 17408 B (32 rows x 33 chunks + tail)
  __shared__ __attribute__((aligned(16))) _Float16 sVt[20*512];  // 20480 B (256 d-rows x 5 chunks)
  __shared__ __attribute__((aligned(16))) _Float16 sP [4][16*PSTR];
  __shared__ __attribute__((aligned(16))) int      sM [KHALF];   // 4 KB int mask

  const int tid  = threadIdx.x;
  const int wave = tid >> 6, lane = tid & 63;
  const int quad = lane >> 4, l16 = lane & 15;
  const int b = blockIdx.y, z = blockIdx.z;
  const int q0w = blockIdx.x*64 + wave*16;

  // ---- Q fragments, register resident ----
  f16x8 qh[8];
  {
    const _Float16* qr = x16 + ((size_t)(b*L_ + q0w + l16))*D_;
    #pragma unroll
    for (int ks=0; ks<8; ++ks)
      qh[ks] = *(const f16x8*)(qr + ks*32 + quad*8);
  }

  // ---- staging tables: 37 slots (17 K + 20 V) round-robined over 4 waves ----
  int nsl = 0;
  unsigned gof[10], lof[10], vsel[10];
  for (int i=0;i<10;i++){
    int slot = wave + i*4;
    if (slot < 17){
      int c = slot*64 + lane;
      int row = c/33, cc = c - row*33;
      if (row > 31){ row = 31; cc = 0; }
      if (cc >= 32) cc = 0;                  // pad/tail chunks -> dummy source
      gof[nsl] = (unsigned)(row*(D_*2) + cc*16);
      lof[nsl] = (unsigned)(slot*1024);
      vsel[nsl] = 0; nsl++;
    } else if (slot < 37){
      int c = (slot-17)*64 + lane;
      int d = c/5, ck = c - d*5;
      if (ck >= 4) ck = 0;
      gof[nsl] = (unsigned)(d*(L_*2) + ck*16);
      lof[nsl] = (unsigned)((slot-17)*1024);
      vsel[nsl] = 1; nsl++;
    }
  }

  // ---- stage this split's int mask (4 KB = 4 slots, one per wave) ----
  {
    const char* ms = (const char*)(mask + b*L_ + z*KHALF) + (unsigned)(wave*1024 + lane*16);
    // note: dest is wave-uniform base; HW appends lane*16
    __builtin_amdgcn_global_load_lds((const __attribute__((address_space(1))) void*)ms,
                                     (__attribute__((address_space(3))) void*)((char*)sM + wave*1024),
                                     16, 0, 0);
  }

  // ---- online softmax state ----
  f32x4 O[16];
  #pragma unroll
  for (int i=0;i<16;i++) O[i] = (f32x4){0.f,0.f,0.f,0.f};
  f32x4 mold = (f32x4){NEG_INF,NEG_INF,NEG_INF,NEG_INF};
  f32x4 lsum = (f32x4){0.f,0.f,0.f,0.f};

  for (int it=0; it<NIT; ++it){
    __syncthreads();   // previous tile consumed (also covers mask staging at it=0)
    {
      const char* kb = (const char*)x16  + ((size_t)b*L_ + (size_t)(z*KHALF + it*BK))*(size_t)(D_*2);
      const char* vb = (const char*)xt16 + ((size_t)b*D_*L_)*2 + (size_t)(z*KHALF + it*BK)*2;
      for (int i=0;i<nsl;i++){
        const char* src = (vsel[i] ? vb : kb) + gof[i];
        char* dst = (vsel[i] ? (char*)sVt : (char*)sK) + lof[i];
        __builtin_amdgcn_global_load_lds((const __attribute__((address_space(1))) void*)src,
                                         (__attribute__((address_space(3))) void*)dst, 16, 0, 0);
      }
    }
    __syncthreads();   // staged tile visible

    // ---- S = Q·K^T (fp16 MFMA), 2 n-tiles of 16 keys ----
    f32x4 S[2];
    S[0]=(f32x4){0.f,0.f,0.f,0.f}; S[1]=(f32x4){0.f,0.f,0.f,0.f};
    #pragma unroll
    for (int ks=0; ks<8; ++ks){
      f16x8 b0 = *(const f16x8*)(sK + (     l16)*KSTR + ks*32 + quad*8);
      f16x8 b1 = *(const f16x8*)(sK + (16 + l16)*KSTR + ks*32 + quad*8);
      S[0] = MFMA16F(qh[ks], b0, S[0]);
      S[1] = MFMA16F(qh[ks], b1, S[1]);
    }

    // ---- diagonal-zero then key padding mask ----
    #pragma unroll
    for (int nt=0; nt<2; ++nt){
      const int kl = it*BK + nt*16 + l16;       // key within split
      const int kg = z*KHALF + kl;              // global key
      const float mk = sM[kl] ? NEG_INF : 0.0f;
      #pragma unroll
      for (int r=0;r<4;++r){
        if (kg == q0w + quad*4 + r) S[nt][r] = 0.0f;
        S[nt][r] += mk;
      }
    }

    // ---- online softmax ----
    f32x4 t = fmax4(S[0], S[1]);
    #pragma unroll
    for (int off=1; off<16; off<<=1){
      f32x4 o;
      o[0]=__shfl_xor(t[0],off); o[1]=__shfl_xor(t[1],off);
      o[2]=__shfl_xor(t[2],off); o[3]=__shfl_xor(t[3],off);
      t = fmax4(t,o);
    }
    f32x4 mnew = fmax4(mold, t);
    f32x4 mx, alpha;
    #pragma unroll
    for (int r=0;r<4;++r){
      mx[r]    = (mnew[r] > NEG_INF) ? mnew[r] : 0.0f;
      alpha[r] = __expf(mold[r] - mx[r]);
    }
    f32x4 P[2];
    #pragma unroll
    for (int nt=0; nt<2; ++nt)
      #pragma unroll
      for (int r=0;r<4;++r)
        P[nt][r] = __expf(S[nt][r] - mx[r]);
    f32x4 rs = P[0] + P[1];
    #pragma unroll
    for (int off=1; off<16; off<<=1){
      f32x4 o;
      o[0]=__shfl_xor(rs[0],off); o[1]=__shfl_xor(rs[1],off);
      o[2]=__shfl_xor(rs[2],off); o[3]=__shfl_xor(rs[3],off);
      rs = rs + o;
    }
    #pragma unroll
    for (int r=0;r<4;++r) lsum[r] = lsum[r]*alpha[r] + rs[r];
    mold = mnew;
    // skip O-rescale when no row max changed (common in later iterations)
    if (__ballot(alpha[0]<1.f || alpha[1]<1.f || alpha[2]<1.f || alpha[3]<1.f)){
      #pragma unroll
      for (int vt=0; vt<16; ++vt) O[vt] *= alpha;
    }

    // ---- P: C-layout -> LDS -> A-layout (fp16) ----
    #pragma unroll
    for (int nt=0; nt<2; ++nt)
      #pragma unroll
      for (int r=0;r<4;++r)
        sP[wave][(quad*4+r)*PSTR + nt*16 + l16] = (_Float16)P[nt][r];
    __threadfence_block();
    f16x8 pf = *(const f16x8*)(&sP[wave][l16*PSTR + quad*8]);

    // ---- O += P · V ----
    #pragma unroll
    for (int vt=0; vt<16; ++vt){
      f16x8 bv = *(const f16x8*)(sVt + (vt*16+l16)*VSTR + quad*8);
      O[vt] = MFMA16F(pf, bv, O[vt]);
    }
  }

  // ---- epilogue: store unnormalized O' + (m, l) for combine ----
  float* ob = z ? out1 : out0;
  #pragma unroll
  for (int vt=0; vt<16; ++vt)
    #pragma unroll
    for (int r=0;r<4;++r)
      ob[((size_t)(b*L_ + q0w + quad*4 + r))*D_ + vt*16 + l16] = O[vt][r];
  if (l16 == 0){
    #pragma unroll
    for (int r=0;r<4;++r){
      int row = b*L_ + q0w + quad*4 + r;
      mlm[z*NROW + row] = mold[r];
      mll[z*NROW + row] = lsum[r];
    }
  }
}

// ---------------- combine the two key-splits ----------------
__global__ void combine_k(float* __restrict__ out,
                          const float* __restrict__ obuf,
                          const float* __restrict__ mlm,
                          const float* __restrict__ mll){
  const int idx = blockIdx.x*256 + threadIdx.x;   // one float4 per thread
  const int row = idx >> 6;                        // 64 float4 per 256-d row
  const float m1 = mlm[row], m2 = mlm[NROW + row];
  const float l1 = mll[row], l2 = mll[NROW + row];
  const float m  = fmaxf(m1, m2);
  const float a1 = __expf(m1 - m), a2 = __expf(m2 - m);
  const float inv = 1.0f / (l1*a1 + l2*a2);
  const float w1 = a1*inv, w2 = a2*inv;
  const float4 o1 = ((const float4*)out)[idx];
  const float4 o2 = ((const float4*)obuf)[idx];
  float4 r;
  r.x = o1.x*w1 + o2.x*w2;
  r.y = o1.y*w1 + o2.y*w2;
  r.z = o1.z*w1 + o2.z*w2;
  r.w = o1.w*w1 + o2.w*w2;
  ((float4*)out)[idx] = r;
}

extern "C" void kernel_launch(void* const* d_in, const int* in_sizes, int n_in,
                              void* d_out, int out_size, void* d_ws, size_t ws_size,
                              hipStream_t stream) {
  const float* x    = (const float*)d_in[0];
  const int*   mask = (const int*)d_in[1];
  float*       out  = (float*)d_out;

  const size_t NE = (size_t)B_*L_*D_;
  _Float16* x16  = (_Float16*)d_ws;
  _Float16* xt16 = x16 + NE;
  float*    obuf = (float*)(xt16 + NE);
  float*    mlm  = obuf + NE;            // 2*NROW floats
  float*    mll  = mlm + 2*NROW;         // 2*NROW floats   (total ~33.9 MB)

  prep_k   <<<dim3(D_/64, L_/64, B_), dim3(256), 0, stream>>>(x, x16, xt16);
  flash_k  <<<dim3(L_/64, B_, KSPLIT), dim3(256), 0, stream>>>(x16, xt16, mask, out, obuf, mlm, mll);
  combine_k<<<dim3((NE/4)/256), dim3(256), 0, stream>>>(out, obuf, mlm, mll);
}

// Round 3
// 212.324 us; speedup vs baseline: 1.2334x; 1.0998x over previous
//
#include <hip/hip_runtime.h>
#include <hip/hip_bf16.h>

#define B_ 8
#define L_ 2048
#define D_ 256
#define BK 32
#define KSPLIT 2
#define KHALF (L_/KSPLIT)      // 1024 keys per split
#define NIT (KHALF/BK)         // 32 iterations
#define KSTR 264               // fp16 elems per K row in LDS (528 B = 33 chunks)
#define PSTR 40
#define NROW (B_*L_)           // 16384

typedef __attribute__((ext_vector_type(8))) _Float16 f16x8;
typedef __attribute__((ext_vector_type(4))) float f32x4;

#define MFMA16F(a,b,c) __builtin_amdgcn_mfma_f32_16x16x32_f16((a),(b),(c),0,0,0)
#define NEG_INF (-__builtin_inff())

__device__ __forceinline__ f32x4 fmax4(f32x4 a, f32x4 b){
  f32x4 r;
  r[0]=fmaxf(a[0],b[0]); r[1]=fmaxf(a[1],b[1]);
  r[2]=fmaxf(a[2],b[2]); r[3]=fmaxf(a[3],b[3]);
  return r;
}

// ---------------- prep: fp32 x -> fp16 x16 (row-major) + xt16 (d-major) ----
__global__ void prep_k(const float* __restrict__ x,
                       _Float16* __restrict__ x16,
                       _Float16* __restrict__ xt16){
  __shared__ _Float16 T[64][66];
  const int t = threadIdx.x;
  const int d0 = blockIdx.x*64, l0 = blockIdx.y*64, b = blockIdx.z;
  const int lr = t>>3, c8 = (t&7)*8;
  #pragma unroll
  for (int p=0;p<2;++p){
    int l = lr + p*32;
    size_t idx = ((size_t)(b*L_ + l0 + l))*D_ + d0 + c8;
    float4 v0 = *(const float4*)(x + idx);
    float4 v1 = *(const float4*)(x + idx + 4);
    f16x8 h;
    h[0]=(_Float16)v0.x; h[1]=(_Float16)v0.y; h[2]=(_Float16)v0.z; h[3]=(_Float16)v0.w;
    h[4]=(_Float16)v1.x; h[5]=(_Float16)v1.y; h[6]=(_Float16)v1.z; h[7]=(_Float16)v1.w;
    *(f16x8*)(x16 + idx) = h;
    #pragma unroll
    for (int j=0;j<8;++j) T[l][c8+j] = h[j];
  }
  __syncthreads();
  const int dd = t>>3, l8 = (t&7)*8;
  #pragma unroll
  for (int p=0;p<2;++p){
    int d = dd + p*32;
    f16x8 a;
    #pragma unroll
    for (int j=0;j<8;++j) a[j] = T[l8+j][d];
    size_t od = ((size_t)(b*D_ + d0 + d))*L_ + l0 + l8;
    *(f16x8*)(xt16 + od) = a;
  }
}

// ---------------- flash attention over one key-split ----------------
// grid (L/128, B, KSPLIT), block 512 = 8 waves; wave owns 16 query rows.
// K double-buffered in LDS (single barrier/iter); V-frags global->register.
__launch_bounds__(512, 2)
__global__ void flash_k(const _Float16* __restrict__ x16,
                        const _Float16* __restrict__ xt16,
                        const int* __restrict__ mask,
                        _Float16* __restrict__ o0,
                        _Float16* __restrict__ o1,
                        float* __restrict__ mlm,
                        float* __restrict__ mll){
  __shared__ __attribute__((aligned(16))) _Float16 sK[2][17*512]; // 2 x 17408 B
  __shared__ __attribute__((aligned(16))) _Float16 sP[8][16*PSTR];// 10240 B
  __shared__ __attribute__((aligned(16))) int      sM[KHALF];     // 4096 B
                                                                  // total 49152 B

  const int tid  = threadIdx.x;
  const int wave = tid >> 6, lane = tid & 63;
  const int quad = lane >> 4, l16 = lane & 15;
  const int b = blockIdx.y, z = blockIdx.z;
  const int q0w = blockIdx.x*128 + wave*16;

  // ---- Q fragments, register resident (A-layout) ----
  f16x8 qh[8];
  {
    const _Float16* qr = x16 + ((size_t)(b*L_ + q0w + l16))*D_;
    #pragma unroll
    for (int ks=0; ks<8; ++ks)
      qh[ks] = *(const f16x8*)(qr + ks*32 + quad*8);
  }

  // ---- K staging: 17 slots round-robined over 8 waves (<=3 per wave) ----
  int nsl = 0;
  unsigned gof[3], lof[3];
  for (int s=wave; s<17; s+=8){
    int c = s*64 + lane;
    int row = c/33, cc = c - row*33;
    if (row > 31){ row = 31; cc = 0; }   // tail chunks -> dummy source
    if (cc >= 32) cc = 0;                // row-pad chunk -> dummy source
    gof[nsl] = (unsigned)(row*(D_*2) + cc*16);
    lof[nsl] = (unsigned)(s*1024);
    nsl++;
  }
  const char* kgb = (const char*)(x16 + ((size_t)b*L_ + (size_t)z*KHALF)*D_);

  // preload tile 0 + mask
  {
    const char* src = kgb;
    char* dst = (char*)sK[0];
    for (int i=0;i<nsl;i++)
      __builtin_amdgcn_global_load_lds((const __attribute__((address_space(1))) void*)(src + gof[i]),
                                       (__attribute__((address_space(3))) void*)(dst + lof[i]), 16, 0, 0);
    if (wave < 4){
      const char* ms = (const char*)(mask + b*L_ + z*KHALF) + (unsigned)(wave*1024 + lane*16);
      __builtin_amdgcn_global_load_lds((const __attribute__((address_space(1))) void*)ms,
                                       (__attribute__((address_space(3))) void*)((char*)sM + wave*1024), 16, 0, 0);
    }
  }

  const _Float16* vb0 = xt16 + (size_t)b*D_*L_ + (size_t)z*KHALF;

  // ---- online softmax state ----
  f32x4 O[16];
  #pragma unroll
  for (int i=0;i<16;i++) O[i] = (f32x4){0.f,0.f,0.f,0.f};
  f32x4 mold = (f32x4){NEG_INF,NEG_INF,NEG_INF,NEG_INF};
  f32x4 lsum = (f32x4){0.f,0.f,0.f,0.f};

  for (int it=0; it<NIT; ++it){
    __syncthreads();   // tile it visible (loads were issued a full iter ago)

    // issue next tile's staging immediately (drained only at NEXT barrier)
    if (it+1 < NIT){
      const char* src = kgb + (size_t)(it+1)*(BK*D_*2);
      char* dst = (char*)sK[(it+1)&1];
      for (int i=0;i<nsl;i++)
        __builtin_amdgcn_global_load_lds((const __attribute__((address_space(1))) void*)(src + gof[i]),
                                         (__attribute__((address_space(3))) void*)(dst + lof[i]), 16, 0, 0);
    }

    // V fragments straight from global (L2/L3-hot), consumed after softmax
    f16x8 vf[16];
    {
      const _Float16* vb = vb0 + it*BK + quad*8;
      #pragma unroll
      for (int vt=0; vt<16; ++vt)
        vf[vt] = *(const f16x8*)(vb + (size_t)(vt*16+l16)*L_);
    }

    // ---- S = Q·K^T ----
    const _Float16* kb = sK[it&1];
    f32x4 S[2];
    S[0]=(f32x4){0.f,0.f,0.f,0.f}; S[1]=(f32x4){0.f,0.f,0.f,0.f};
    #pragma unroll
    for (int ks=0; ks<8; ++ks){
      f16x8 b0 = *(const f16x8*)(kb + (     l16)*KSTR + ks*32 + quad*8);
      f16x8 b1 = *(const f16x8*)(kb + (16 + l16)*KSTR + ks*32 + quad*8);
      S[0] = MFMA16F(qh[ks], b0, S[0]);
      S[1] = MFMA16F(qh[ks], b1, S[1]);
    }

    // ---- diagonal-zero then key padding mask ----
    #pragma unroll
    for (int nt=0; nt<2; ++nt){
      const int kl = it*BK + nt*16 + l16;
      const int kg = z*KHALF + kl;
      const float mk = sM[kl] ? NEG_INF : 0.0f;
      #pragma unroll
      for (int r=0;r<4;++r){
        if (kg == q0w + quad*4 + r) S[nt][r] = 0.0f;
        S[nt][r] += mk;
      }
    }

    // ---- online softmax ----
    f32x4 t = fmax4(S[0], S[1]);
    #pragma unroll
    for (int off=1; off<16; off<<=1){
      f32x4 o;
      o[0]=__shfl_xor(t[0],off); o[1]=__shfl_xor(t[1],off);
      o[2]=__shfl_xor(t[2],off); o[3]=__shfl_xor(t[3],off);
      t = fmax4(t,o);
    }
    f32x4 mnew = fmax4(mold, t);
    f32x4 mx, alpha;
    #pragma unroll
    for (int r=0;r<4;++r){
      mx[r]    = (mnew[r] > NEG_INF) ? mnew[r] : 0.0f;
      alpha[r] = __expf(mold[r] - mx[r]);
    }
    f32x4 P[2];
    #pragma unroll
    for (int nt=0; nt<2; ++nt)
      #pragma unroll
      for (int r=0;r<4;++r)
        P[nt][r] = __expf(S[nt][r] - mx[r]);
    f32x4 rs = P[0] + P[1];
    #pragma unroll
    for (int off=1; off<16; off<<=1){
      f32x4 o;
      o[0]=__shfl_xor(rs[0],off); o[1]=__shfl_xor(rs[1],off);
      o[2]=__shfl_xor(rs[2],off); o[3]=__shfl_xor(rs[3],off);
      rs = rs + o;
    }
    #pragma unroll
    for (int r=0;r<4;++r) lsum[r] = lsum[r]*alpha[r] + rs[r];
    mold = mnew;
    if (__ballot(alpha[0]<1.f || alpha[1]<1.f || alpha[2]<1.f || alpha[3]<1.f)){
      #pragma unroll
      for (int vt=0; vt<16; ++vt) O[vt] *= alpha;
    }

    // ---- P: C-layout -> LDS -> A-layout (wave-private, no barrier) ----
    #pragma unroll
    for (int nt=0; nt<2; ++nt)
      #pragma unroll
      for (int r=0;r<4;++r)
        sP[wave][(quad*4+r)*PSTR + nt*16 + l16] = (_Float16)P[nt][r];
    __threadfence_block();
    f16x8 pf = *(const f16x8*)(&sP[wave][l16*PSTR + quad*8]);

    // ---- O += P · V ----
    #pragma unroll
    for (int vt=0; vt<16; ++vt)
      O[vt] = MFMA16F(pf, vf[vt], O[vt]);
  }

  // ---- epilogue: unnormalized O' (fp16) + (m, l) per row ----
  _Float16* ob = z ? o1 : o0;
  #pragma unroll
  for (int vt=0; vt<16; ++vt)
    #pragma unroll
    for (int r=0;r<4;++r)
      ob[((size_t)(b*L_ + q0w + quad*4 + r))*D_ + vt*16 + l16] = (_Float16)O[vt][r];
  if (l16 == 0){
    #pragma unroll
    for (int r=0;r<4;++r){
      int row = b*L_ + q0w + quad*4 + r;
      mlm[z*NROW + row] = mold[r];
      mll[z*NROW + row] = lsum[r];
    }
  }
}

// ---------------- combine the two key-splits ----------------
__global__ void combine_k(float* __restrict__ out,
                          const _Float16* __restrict__ o0,
                          const _Float16* __restrict__ o1,
                          const float* __restrict__ mlm,
                          const float* __restrict__ mll){
  const int idx = blockIdx.x*256 + threadIdx.x;   // one f16x8 pair per thread
  const int row = idx >> 5;                        // 32 groups of 8 per 256-d row
  const float m1 = mlm[row], m2 = mlm[NROW + row];
  const float l1 = mll[row], l2 = mll[NROW + row];
  const float m  = fmaxf(m1, m2);
  const float a1 = __expf(m1 - m), a2 = __expf(m2 - m);
  const float inv = 1.0f / (l1*a1 + l2*a2);
  const float w1 = a1*inv, w2 = a2*inv;
  f16x8 u = ((const f16x8*)o0)[idx];
  f16x8 v = ((const f16x8*)o1)[idx];
  float* op = out + (size_t)idx*8;
  #pragma unroll
  for (int j=0;j<8;++j) op[j] = (float)u[j]*w1 + (float)v[j]*w2;
}

extern "C" void kernel_launch(void* const* d_in, const int* in_sizes, int n_in,
                              void* d_out, int out_size, void* d_ws, size_t ws_size,
                              hipStream_t stream) {
  const float* x    = (const float*)d_in[0];
  const int*   mask = (const int*)d_in[1];
  float*       out  = (float*)d_out;

  const size_t NE = (size_t)B_*L_*D_;
  _Float16* x16  = (_Float16*)d_ws;
  _Float16* xt16 = x16 + NE;
  _Float16* o0   = xt16 + NE;
  _Float16* o1   = o0 + NE;
  float*    mlm  = (float*)(o1 + NE);    // 2*NROW floats
  float*    mll  = mlm + 2*NROW;         // 2*NROW floats (total ~33.8 MB)

  prep_k   <<<dim3(D_/64, L_/64, B_), dim3(256), 0, stream>>>(x, x16, xt16);
  flash_k  <<<dim3(L_/128, B_, KSPLIT), dim3(512), 0, stream>>>(x16, xt16, mask, o0, o1, mlm, mll);
  combine_k<<<dim3((int)(NE/8/256)), dim3(256), 0, stream>>>(out, o0, o1, mlm, mll);
}

// Round 4
// 197.537 us; speedup vs baseline: 1.3257x; 1.0749x over previous
//
#include <hip/hip_runtime.h>
#include <hip/hip_bf16.h>

#define B_ 8
#define L_ 2048
#define D_ 256
#define BK 32
#define KSPLIT 4
#define KQ (L_/KSPLIT)         // 512 keys per split
#define NIT (KQ/BK)            // 16 iterations
#define PSTR 40
#define NROW (B_*L_)           // 16384

typedef __attribute__((ext_vector_type(8))) _Float16 f16x8;
typedef __attribute__((ext_vector_type(4))) float f32x4;

#define MFMA16F(a,b,c) __builtin_amdgcn_mfma_f32_16x16x32_f16((a),(b),(c),0,0,0)
#define NEG_INF (-__builtin_inff())
#define GLL(src,dst) __builtin_amdgcn_global_load_lds( \
    (const __attribute__((address_space(1))) void*)(src), \
    (__attribute__((address_space(3))) void*)(dst), 16, 0, 0)

__device__ __forceinline__ f32x4 fmax4(f32x4 a, f32x4 b){
  f32x4 r;
  r[0]=fmaxf(a[0],b[0]); r[1]=fmaxf(a[1],b[1]);
  r[2]=fmaxf(a[2],b[2]); r[3]=fmaxf(a[3],b[3]);
  return r;
}

// ---------------- prep: fp32 x -> fp16 x16 (row-major) + xt16 (d-major) ----
__global__ void prep_k(const float* __restrict__ x,
                       _Float16* __restrict__ x16,
                       _Float16* __restrict__ xt16){
  __shared__ _Float16 T[64][66];
  const int t = threadIdx.x;
  const int d0 = blockIdx.x*64, l0 = blockIdx.y*64, b = blockIdx.z;
  const int lr = t>>3, c8 = (t&7)*8;
  #pragma unroll
  for (int p=0;p<2;++p){
    int l = lr + p*32;
    size_t idx = ((size_t)(b*L_ + l0 + l))*D_ + d0 + c8;
    float4 v0 = *(const float4*)(x + idx);
    float4 v1 = *(const float4*)(x + idx + 4);
    f16x8 h;
    h[0]=(_Float16)v0.x; h[1]=(_Float16)v0.y; h[2]=(_Float16)v0.z; h[3]=(_Float16)v0.w;
    h[4]=(_Float16)v1.x; h[5]=(_Float16)v1.y; h[6]=(_Float16)v1.z; h[7]=(_Float16)v1.w;
    *(f16x8*)(x16 + idx) = h;
    #pragma unroll
    for (int j=0;j<8;++j) T[l][c8+j] = h[j];
  }
  __syncthreads();
  const int dd = t>>3, l8 = (t&7)*8;
  #pragma unroll
  for (int p=0;p<2;++p){
    int d = dd + p*32;
    f16x8 a;
    #pragma unroll
    for (int j=0;j<8;++j) a[j] = T[l8+j][d];
    size_t od = ((size_t)(b*D_ + d0 + d))*L_ + l0 + l8;
    *(f16x8*)(xt16 + od) = a;
  }
}

// ---------------- prep: mask -> per-(b,z,l16) 32-bit key bitmask ----------
__global__ void maskbits_k(const int* __restrict__ mask,
                           unsigned* __restrict__ mbits){
  const int t = blockIdx.x*256 + threadIdx.x;   // 512 entries
  if (t >= B_*KSPLIT*16) return;
  const int b = t>>6, z = (t>>4)&3, l16 = t&15;
  unsigned v = 0;
  #pragma unroll
  for (int j=0;j<32;++j)
    v |= (mask[b*L_ + z*KQ + j*16 + l16] ? 1u : 0u) << j;
  mbits[t] = v;
}

// ---------------- flash attention over one key-split ----------------------
// grid (L/128, B, KSPLIT), block 256 = 4 waves; wave owns 32 query rows.
// Single-buffered K,V tiles; 2 barriers/iter; staging drains 1 barrier late.
__launch_bounds__(256, 2)
__global__ void flash_k(const _Float16* __restrict__ x16,
                        const _Float16* __restrict__ xt16,
                        const unsigned* __restrict__ mbitsg,
                        _Float16* __restrict__ oall,
                        float* __restrict__ mlm,
                        float* __restrict__ mll){
  __shared__ __attribute__((aligned(16))) _Float16 sK[BK*512/2*2];   // 16 KB: 32 rows x 512B, xor-swizzled
  __shared__ __attribute__((aligned(16))) _Float16 sV[D_*32];        // 16 KB: 256 rows x 64B, xor-swizzled
  __shared__ __attribute__((aligned(16))) _Float16 sP[4][32*PSTR];   // 10 KB

  const int tid  = threadIdx.x;
  const int wave = tid >> 6, lane = tid & 63;
  const int quad = lane >> 4, l16 = lane & 15;
  const int b = blockIdx.y, z = blockIdx.z;
  const int q0w = blockIdx.x*128 + wave*32;

  // ---- Q fragments: 2 rowsets x 8 k-steps ----
  f16x8 qh[2][8];
  #pragma unroll
  for (int rs=0; rs<2; ++rs){
    const _Float16* qr = x16 + ((size_t)(b*L_ + q0w + rs*16 + l16))*D_;
    #pragma unroll
    for (int ks=0; ks<8; ++ks)
      qh[rs][ks] = *(const f16x8*)(qr + ks*32 + quad*8);
  }

  // ---- mask bits for this lane's key column ----
  const unsigned mb = mbitsg[(b*KSPLIT + z)*16 + l16];

  // ---- staging source-offset tables (swizzle folded into source) ----
  // K: 16 slots of 64 chunks; chunk c: row r=c>>5, phys=c&31, logical=phys^(r&7)
  // V: 16 slots;              chunk c: row d=c>>2, phys=c&3,  logical=phys^((d>>1)&3)
  unsigned kof[4], vof[4];
  #pragma unroll
  for (int i=0;i<4;++i){
    int c = (wave + i*4)*64 + lane;
    int r = c>>5, pk = c&31;
    kof[i] = (unsigned)(r*512 + ((pk ^ (r&7))*16));
    int d = c>>2, pv = c&3;
    vof[i] = (unsigned)(d*(L_*2) + ((pv ^ ((d>>1)&3))*16));
  }
  const char* kbase = (const char*)(x16 + ((size_t)b*L_ + (size_t)z*KQ)*D_);
  const char* vbase = (const char*)(xt16 + (size_t)b*D_*L_) + (size_t)(z*KQ)*2;
  char* kdst0 = (char*)sK + wave*1024;
  char* vdst0 = (char*)sV + wave*1024;

  // ---- preload tile 0 ----
  #pragma unroll
  for (int i=0;i<4;++i) GLL(kbase + kof[i], kdst0 + i*4096);
  #pragma unroll
  for (int i=0;i<4;++i) GLL(vbase + vof[i], vdst0 + i*4096);

  // ---- softmax state ----
  f32x4 O[2][16], Osum[2];
  #pragma unroll
  for (int rs=0; rs<2; ++rs){
    #pragma unroll
    for (int i=0;i<16;i++) O[rs][i] = (f32x4){0.f,0.f,0.f,0.f};
    Osum[rs] = (f32x4){0.f,0.f,0.f,0.f};
  }
  f32x4 mold[2] = {(f32x4){NEG_INF,NEG_INF,NEG_INF,NEG_INF},
                   (f32x4){NEG_INF,NEG_INF,NEG_INF,NEG_INF}};
  f16x8 ones;
  #pragma unroll
  for (int j=0;j<8;++j) ones[j] = (_Float16)1.0f;

  __syncthreads();   // tile 0 staged & visible

  for (int it=0; it<NIT; ++it){
    // ---- S = Q·K^T (swizzled reads, shared B-frag for both rowsets) ----
    f32x4 S[2][2];
    #pragma unroll
    for (int rs=0;rs<2;++rs){ S[rs][0]=(f32x4){0.f,0.f,0.f,0.f}; S[rs][1]=(f32x4){0.f,0.f,0.f,0.f}; }
    const int sw = l16 & 7;
    #pragma unroll
    for (int ks=0; ks<8; ++ks){
      f16x8 b0 = *(const f16x8*)(sK + (     l16)*256 + (((ks*4+quad)^sw)*8));
      f16x8 b1 = *(const f16x8*)(sK + (16 + l16)*256 + (((ks*4+quad)^sw)*8));
      #pragma unroll
      for (int rs=0; rs<2; ++rs){
        S[rs][0] = MFMA16F(qh[rs][ks], b0, S[rs][0]);
        S[rs][1] = MFMA16F(qh[rs][ks], b1, S[rs][1]);
      }
    }

    __syncthreads();   // B1: all QK reads done; V(it) staging (from prev tail) drained

    // issue K(it+1) into sK (drains at B2)
    if (it+1 < NIT){
      const char* kb = kbase + (size_t)(it+1)*(BK*D_*2);
      #pragma unroll
      for (int i=0;i<4;++i) GLL(kb + kof[i], kdst0 + i*4096);
    }

    // ---- diag-zero, key mask, online softmax ----
    f16x8 pf[2];
    #pragma unroll
    for (int rs=0; rs<2; ++rs){
      #pragma unroll
      for (int nt=0; nt<2; ++nt){
        const int kg = z*KQ + it*BK + nt*16 + l16;
        const float mk = ((mb >> (unsigned)(it*2+nt)) & 1u) ? NEG_INF : 0.0f;
        const int row0 = q0w + rs*16 + quad*4;
        #pragma unroll
        for (int r=0;r<4;++r){
          if (kg == row0 + r) S[rs][nt][r] = 0.0f;
          S[rs][nt][r] += mk;
        }
      }
      f32x4 t = fmax4(S[rs][0], S[rs][1]);
      #pragma unroll
      for (int off=1; off<16; off<<=1){
        f32x4 o;
        o[0]=__shfl_xor(t[0],off); o[1]=__shfl_xor(t[1],off);
        o[2]=__shfl_xor(t[2],off); o[3]=__shfl_xor(t[3],off);
        t = fmax4(t,o);
      }
      f32x4 mnew = fmax4(mold[rs], t);
      f32x4 mx, alpha;
      #pragma unroll
      for (int r=0;r<4;++r){
        mx[r]    = (mnew[r] > NEG_INF) ? mnew[r] : 0.0f;
        alpha[r] = __expf(mold[rs][r] - mx[r]);
      }
      f32x4 P0, P1;
      #pragma unroll
      for (int r=0;r<4;++r){
        P0[r] = __expf(S[rs][0][r] - mx[r]);
        P1[r] = __expf(S[rs][1][r] - mx[r]);
      }
      mold[rs] = mnew;
      if (__ballot(alpha[0]<1.f || alpha[1]<1.f || alpha[2]<1.f || alpha[3]<1.f)){
        #pragma unroll
        for (int vt=0; vt<16; ++vt) O[rs][vt] *= alpha;
        Osum[rs] *= alpha;
      }
      // P: C-layout -> LDS -> A-layout (wave-private)
      #pragma unroll
      for (int r=0;r<4;++r){
        sP[wave][(rs*16 + quad*4+r)*PSTR +      l16] = (_Float16)P0[r];
        sP[wave][(rs*16 + quad*4+r)*PSTR + 16 + l16] = (_Float16)P1[r];
      }
    }
    __threadfence_block();
    pf[0] = *(const f16x8*)(&sP[wave][(     l16)*PSTR + quad*8]);
    pf[1] = *(const f16x8*)(&sP[wave][(16 + l16)*PSTR + quad*8]);

    // ---- O += P·V ; row-sum via ones-MFMA ----
    const int vsw = (l16>>1)&3;
    #pragma unroll
    for (int vt=0; vt<16; ++vt){
      f16x8 bv = *(const f16x8*)(sV + (vt*16+l16)*32 + ((quad^vsw)*8));
      O[0][vt] = MFMA16F(pf[0], bv, O[0][vt]);
      O[1][vt] = MFMA16F(pf[1], bv, O[1][vt]);
    }
    Osum[0] = MFMA16F(pf[0], ones, Osum[0]);
    Osum[1] = MFMA16F(pf[1], ones, Osum[1]);

    __syncthreads();   // B2: all PV reads done; K(it+1) staging drained

    // issue V(it+1) into sV (drains at next B1)
    if (it+1 < NIT){
      const char* vb = vbase + (size_t)(it+1)*(BK*2);
      #pragma unroll
      for (int i=0;i<4;++i) GLL(vb + vof[i], vdst0 + i*4096);
    }
  }

  // ---- epilogue: unnormalized O' (fp16) + (m, l) per row ----
  _Float16* ob = oall + (size_t)z*NROW*D_;
  #pragma unroll
  for (int rs=0; rs<2; ++rs){
    #pragma unroll
    for (int vt=0; vt<16; ++vt)
      #pragma unroll
      for (int r=0;r<4;++r)
        ob[((size_t)(b*L_ + q0w + rs*16 + quad*4 + r))*D_ + vt*16 + l16] = (_Float16)O[rs][vt][r];
    if (l16 == 0){
      #pragma unroll
      for (int r=0;r<4;++r){
        int row = b*L_ + q0w + rs*16 + quad*4 + r;
        mlm[z*NROW + row] = mold[rs][r];
        mll[z*NROW + row] = Osum[rs][r];
      }
    }
  }
}

// ---------------- combine the four key-splits ----------------
__global__ void combine_k(float* __restrict__ out,
                          const _Float16* __restrict__ oall,
                          const float* __restrict__ mlm,
                          const float* __restrict__ mll){
  const int idx = blockIdx.x*256 + threadIdx.x;   // one f16x8 per thread
  const int row = idx >> 5;                        // 32 groups of 8 per 256-d row
  float m = NEG_INF, mz[KSPLIT], lz[KSPLIT];
  #pragma unroll
  for (int zc=0; zc<KSPLIT; ++zc){
    mz[zc] = mlm[zc*NROW + row];
    lz[zc] = mll[zc*NROW + row];
    m = fmaxf(m, mz[zc]);
  }
  float den = 0.f, az[KSPLIT];
  #pragma unroll
  for (int zc=0; zc<KSPLIT; ++zc){
    az[zc] = __expf(mz[zc] - m);
    den += lz[zc]*az[zc];
  }
  const float inv = 1.0f/den;
  float acc[8];
  #pragma unroll
  for (int j=0;j<8;++j) acc[j] = 0.f;
  const size_t NE8 = (size_t)NROW*D_/8;
  #pragma unroll
  for (int zc=0; zc<KSPLIT; ++zc){
    f16x8 u = ((const f16x8*)oall)[zc*NE8 + idx];
    const float w = az[zc]*inv;
    #pragma unroll
    for (int j=0;j<8;++j) acc[j] += (float)u[j]*w;
  }
  float* op = out + (size_t)idx*8;
  #pragma unroll
  for (int j=0;j<8;++j) op[j] = acc[j];
}

extern "C" void kernel_launch(void* const* d_in, const int* in_sizes, int n_in,
                              void* d_out, int out_size, void* d_ws, size_t ws_size,
                              hipStream_t stream) {
  const float* x    = (const float*)d_in[0];
  const int*   mask = (const int*)d_in[1];
  float*       out  = (float*)d_out;

  const size_t NE = (size_t)B_*L_*D_;
  _Float16* x16  = (_Float16*)d_ws;
  _Float16* xt16 = x16 + NE;
  _Float16* oall = xt16 + NE;               // KSPLIT*NE fp16
  float*    mlm  = (float*)(oall + (size_t)KSPLIT*NE);
  float*    mll  = mlm + (size_t)KSPLIT*NROW;
  unsigned* mbits= (unsigned*)(mll + (size_t)KSPLIT*NROW);  // 512 u32 (~51 MB total)

  prep_k    <<<dim3(D_/64, L_/64, B_), dim3(256), 0, stream>>>(x, x16, xt16);
  maskbits_k<<<dim3(2), dim3(256), 0, stream>>>(mask, mbits);
  flash_k   <<<dim3(L_/128, B_, KSPLIT), dim3(256), 0, stream>>>(x16, xt16, mbits, oall, mlm, mll);
  combine_k <<<dim3((int)(NE/8/256)), dim3(256), 0, stream>>>(out, oall, mlm, mll);
}

// Round 5
// 185.415 us; speedup vs baseline: 1.4124x; 1.0654x over previous
//
#include <hip/hip_runtime.h>
#include <hip/hip_bf16.h>

#define B_ 8
#define L_ 2048
#define D_ 256
#define BK 32
#define KSPLIT 4
#define KQ (L_/KSPLIT)         // 512 keys per split
#define NIT (KQ/BK)            // 16 iterations
#define PSTR 40
#define NROW (B_*L_)           // 16384
#define NE ((size_t)B_*L_*D_)  // 4194304

typedef __attribute__((ext_vector_type(8))) _Float16 f16x8;
typedef __attribute__((ext_vector_type(4))) _Float16 hf4;
typedef __attribute__((ext_vector_type(4))) float f32x4;

#define MFMA16F(a,b,c) __builtin_amdgcn_mfma_f32_16x16x32_f16((a),(b),(c),0,0,0)
#define NEG_INF (-__builtin_inff())
#define GLL(src,dst) __builtin_amdgcn_global_load_lds( \
    (const __attribute__((address_space(1))) void*)(src), \
    (__attribute__((address_space(3))) void*)(dst), 16, 0, 0)

__device__ __forceinline__ f32x4 fmax4(f32x4 a, f32x4 b){
  f32x4 r;
  r[0]=fmaxf(a[0],b[0]); r[1]=fmaxf(a[1],b[1]);
  r[2]=fmaxf(a[2],b[2]); r[3]=fmaxf(a[3],b[3]);
  return r;
}

// ---- prep: fp32 x -> fp16 x16 (row-major) + vtl (pre-tiled V^T, swizzled) ----
// vtl tile kt (32 keys): [256 d][4 chunks][8 keys], chunk at phys = logical ^ ((d>>1)&3)
__global__ void prep_k(const float* __restrict__ x,
                       _Float16* __restrict__ x16,
                       _Float16* __restrict__ vtl){
  __shared__ _Float16 T[64][66];
  const int t = threadIdx.x;
  const int d0 = blockIdx.x*64, l0 = blockIdx.y*64, b = blockIdx.z;
  const int lr = t>>3, c8 = (t&7)*8;
  #pragma unroll
  for (int pp=0;pp<2;++pp){
    int l = lr + pp*32;
    size_t idx = ((size_t)(b*L_ + l0 + l))*D_ + d0 + c8;
    float4 v0 = *(const float4*)(x + idx);
    float4 v1 = *(const float4*)(x + idx + 4);
    f16x8 h;
    h[0]=(_Float16)v0.x; h[1]=(_Float16)v0.y; h[2]=(_Float16)v0.z; h[3]=(_Float16)v0.w;
    h[4]=(_Float16)v1.x; h[5]=(_Float16)v1.y; h[6]=(_Float16)v1.z; h[7]=(_Float16)v1.w;
    *(f16x8*)(x16 + idx) = h;
    #pragma unroll
    for (int j=0;j<8;++j) T[l][c8+j] = h[j];
  }
  __syncthreads();
  const int dd = t>>3, l8 = (t&7)*8;
  #pragma unroll
  for (int pp=0;pp<2;++pp){
    int dloc = dd + pp*32, dg = d0 + dloc;
    f16x8 a;
    #pragma unroll
    for (int j=0;j<8;++j) a[j] = T[l8+j][dloc];
    int kg0 = l0 + l8;
    int kt  = kg0 >> 5;                       // global key-tile (0..63)
    int ph  = ((kg0 & 31) >> 3) ^ ((dg>>1)&3);
    size_t off = ((size_t)(b*64 + kt))*8192 + (size_t)dg*32 + ph*8;
    *(f16x8*)(vtl + off) = a;
  }
}

// ---- flash attention over one key-split ----
// grid (L/128, B, KSPLIT), block 256 = 4 waves; wave owns 32 q-rows (2 rowsets).
// K and V double-buffered in LDS; ONE barrier per iter; staging issued at iter
// top into the other buffer, drained at the iter-end barrier (full-iter cover).
__launch_bounds__(256, 2)
__global__ void flash_k(const _Float16* __restrict__ x16,
                        const _Float16* __restrict__ vtl,
                        const int* __restrict__ mask,
                        _Float16* __restrict__ oall,
                        float* __restrict__ mlm,
                        float* __restrict__ mll){
  __shared__ __attribute__((aligned(16))) _Float16 sK[2][8192];   // 2 x 16 KB
  __shared__ __attribute__((aligned(16))) _Float16 sV[2][8192];   // 2 x 16 KB
  __shared__ __attribute__((aligned(16))) _Float16 sP[4][32*PSTR];// 10 KB

  const int tid  = threadIdx.x;
  const int wave = tid >> 6, lane = tid & 63;
  const int quad = lane >> 4, l16 = lane & 15;
  const int b = blockIdx.y, z = blockIdx.z;
  const int q0w = blockIdx.x*128 + wave*32;

  // ---- Q fragments: 2 rowsets x 8 k-steps (register resident) ----
  f16x8 qh[2][8];
  #pragma unroll
  for (int rs=0; rs<2; ++rs){
    const _Float16* qr = x16 + ((size_t)(b*L_ + q0w + rs*16 + l16))*D_;
    #pragma unroll
    for (int ks=0; ks<8; ++ks)
      qh[rs][ks] = *(const f16x8*)(qr + ks*32 + quad*8);
  }

  // ---- mask bits: 32 keys per lane (key = z*KQ + j*16 + l16) ----
  unsigned mb = 0;
  {
    const int* mrow = mask + b*L_ + z*KQ;
    #pragma unroll
    for (int j=0;j<32;++j) mb |= (mrow[j*16 + l16] ? 1u : 0u) << j;
  }

  // ---- staging offset tables ----
  unsigned kof[4], vof[4], dof[4];
  #pragma unroll
  for (int i=0;i<4;++i){
    int c = (wave + i*4)*64 + lane;
    int r = c>>5, pk = c&31;
    kof[i] = (unsigned)(r*512 + ((pk ^ (r&7))*16));   // K source swizzle
    vof[i] = (unsigned)(c*16);                        // V pre-tiled: linear
    dof[i] = (unsigned)((wave + i*4)*1024);           // LDS uniform base
  }
  const char* kbase = (const char*)x16 + ((size_t)b*L_ + (size_t)z*KQ)*(D_*2);
  const char* vbase = (const char*)vtl + ((size_t)(b*64 + z*16))*16384;

  // ---- preload tile 0 into buffer 0 ----
  #pragma unroll
  for (int i=0;i<4;++i){
    GLL(kbase + kof[i], (char*)sK[0] + dof[i]);
    GLL(vbase + vof[i], (char*)sV[0] + dof[i]);
  }

  // ---- softmax state ----
  f32x4 O[2][16], Osum[2];
  #pragma unroll
  for (int rs=0; rs<2; ++rs){
    #pragma unroll
    for (int i=0;i<16;i++) O[rs][i] = (f32x4){0.f,0.f,0.f,0.f};
    Osum[rs] = (f32x4){0.f,0.f,0.f,0.f};
  }
  f32x4 mold[2] = {(f32x4){NEG_INF,NEG_INF,NEG_INF,NEG_INF},
                   (f32x4){NEG_INF,NEG_INF,NEG_INF,NEG_INF}};
  f16x8 ones;
  #pragma unroll
  for (int j=0;j<8;++j) ones[j] = (_Float16)1.0f;

  __syncthreads();   // tile 0 staged & visible

  for (int it=0; it<NIT; ++it){
    // issue next tile into the other buffer; drains at THIS iter's end barrier
    if (it+1 < NIT){
      const char* kb = kbase + (size_t)(it+1)*16384;
      const char* vb = vbase + (size_t)(it+1)*16384;
      char* kd = (char*)sK[(it+1)&1];
      char* vd = (char*)sV[(it+1)&1];
      #pragma unroll
      for (int i=0;i<4;++i){
        GLL(kb + kof[i], kd + dof[i]);
        GLL(vb + vof[i], vd + dof[i]);
      }
    }
    const _Float16* kb = sK[it&1];
    const _Float16* vb = sV[it&1];

    // ---- S = Q·K^T (swizzled K reads; B-frag shared across rowsets) ----
    f32x4 S[2][2];
    #pragma unroll
    for (int rs=0;rs<2;++rs){ S[rs][0]=(f32x4){0.f,0.f,0.f,0.f}; S[rs][1]=(f32x4){0.f,0.f,0.f,0.f}; }
    const int sw = l16 & 7;
    #pragma unroll
    for (int ks=0; ks<8; ++ks){
      f16x8 b0 = *(const f16x8*)(kb + (     l16)*256 + (((ks*4+quad)^sw)*8));
      f16x8 b1 = *(const f16x8*)(kb + (16 + l16)*256 + (((ks*4+quad)^sw)*8));
      #pragma unroll
      for (int rs=0; rs<2; ++rs){
        S[rs][0] = MFMA16F(qh[rs][ks], b0, S[rs][0]);
        S[rs][1] = MFMA16F(qh[rs][ks], b1, S[rs][1]);
      }
    }

    // ---- diag-zero, key mask, online softmax ----
    #pragma unroll
    for (int rs=0; rs<2; ++rs){
      #pragma unroll
      for (int nt=0; nt<2; ++nt){
        const int kg = z*KQ + it*BK + nt*16 + l16;
        const float mk = ((mb >> (unsigned)(it*2+nt)) & 1u) ? NEG_INF : 0.0f;
        const int row0 = q0w + rs*16 + quad*4;
        #pragma unroll
        for (int r=0;r<4;++r){
          if (kg == row0 + r) S[rs][nt][r] = 0.0f;
          S[rs][nt][r] += mk;
        }
      }
      f32x4 t = fmax4(S[rs][0], S[rs][1]);
      #pragma unroll
      for (int off=1; off<16; off<<=1){
        f32x4 o;
        o[0]=__shfl_xor(t[0],off); o[1]=__shfl_xor(t[1],off);
        o[2]=__shfl_xor(t[2],off); o[3]=__shfl_xor(t[3],off);
        t = fmax4(t,o);
      }
      f32x4 mnew = fmax4(mold[rs], t);
      f32x4 mx, alpha;
      #pragma unroll
      for (int r=0;r<4;++r){
        mx[r]    = (mnew[r] > NEG_INF) ? mnew[r] : 0.0f;
        alpha[r] = __expf(mold[rs][r] - mx[r]);
      }
      f32x4 P0, P1;
      #pragma unroll
      for (int r=0;r<4;++r){
        P0[r] = __expf(S[rs][0][r] - mx[r]);
        P1[r] = __expf(S[rs][1][r] - mx[r]);
      }
      mold[rs] = mnew;
      if (__ballot(alpha[0]<1.f || alpha[1]<1.f || alpha[2]<1.f || alpha[3]<1.f)){
        #pragma unroll
        for (int vt=0; vt<16; ++vt) O[rs][vt] *= alpha;
        Osum[rs] *= alpha;
      }
      #pragma unroll
      for (int r=0;r<4;++r){
        sP[wave][(rs*16 + quad*4+r)*PSTR +      l16] = (_Float16)P0[r];
        sP[wave][(rs*16 + quad*4+r)*PSTR + 16 + l16] = (_Float16)P1[r];
      }
    }
    __threadfence_block();
    f16x8 pf[2];
    pf[0] = *(const f16x8*)(&sP[wave][(     l16)*PSTR + quad*8]);
    pf[1] = *(const f16x8*)(&sP[wave][(16 + l16)*PSTR + quad*8]);

    // ---- O += P·V ; row-sum via ones-MFMA (V-frag shared across rowsets) ----
    const int vsw = (l16>>1)&3;
    #pragma unroll
    for (int vt=0; vt<16; ++vt){
      f16x8 bv = *(const f16x8*)(vb + (vt*16+l16)*32 + ((quad^vsw)*8));
      O[0][vt] = MFMA16F(pf[0], bv, O[0][vt]);
      O[1][vt] = MFMA16F(pf[1], bv, O[1][vt]);
    }
    Osum[0] = MFMA16F(pf[0], ones, Osum[0]);
    Osum[1] = MFMA16F(pf[1], ones, Osum[1]);

    __syncthreads();   // protects buffer reuse + drains next-tile staging
  }

  // ---- epilogue: fragment-major coalesced fp16 stores + (m,l) ----
  #pragma unroll
  for (int rs=0; rs<2; ++rs){
    const int u = ((b*16 + blockIdx.x)*4 + wave)*2 + rs;   // row-group [0,1024)
    _Float16* ob = oall + (size_t)z*NE + (size_t)u*4096;
    #pragma unroll
    for (int vt=0; vt<16; ++vt){
      hf4 h;
      #pragma unroll
      for (int r=0;r<4;++r) h[r] = (_Float16)O[rs][vt][r];
      *(hf4*)(ob + vt*256 + lane*4) = h;
    }
    if (l16 == 0){
      #pragma unroll
      for (int r=0;r<4;++r){
        int row = u*16 + quad*4 + r;
        mlm[z*NROW + row] = mold[rs][r];
        mll[z*NROW + row] = Osum[rs][r];
      }
    }
  }
}

// ---- combine the key-splits (decodes fragment-major oall layout) ----
__global__ void combine_k(float* __restrict__ out,
                          const _Float16* __restrict__ oall,
                          const float* __restrict__ mlm,
                          const float* __restrict__ mll){
  const int t = blockIdx.x*256 + threadIdx.x;   // [0, NE/4)
  const int u = t>>10, vt = (t>>6)&15, lane = t&63;
  const int quad = lane>>4, l16 = lane&15;
  const int row0 = u*16 + quad*4;
  float4 mz[KSPLIT], lz[KSPLIT];
  float m[4] = {NEG_INF,NEG_INF,NEG_INF,NEG_INF};
  #pragma unroll
  for (int zc=0; zc<KSPLIT; ++zc){
    mz[zc] = *(const float4*)(mlm + zc*NROW + row0);
    lz[zc] = *(const float4*)(mll + zc*NROW + row0);
    m[0]=fmaxf(m[0],mz[zc].x); m[1]=fmaxf(m[1],mz[zc].y);
    m[2]=fmaxf(m[2],mz[zc].z); m[3]=fmaxf(m[3],mz[zc].w);
  }
  float az[KSPLIT][4], den[4]={0.f,0.f,0.f,0.f};
  #pragma unroll
  for (int zc=0; zc<KSPLIT; ++zc){
    const float* mzp = (const float*)&mz[zc];
    const float* lzp = (const float*)&lz[zc];
    #pragma unroll
    for (int r=0;r<4;++r){
      az[zc][r] = __expf(mzp[r] - m[r]);
      den[r] += lzp[r]*az[zc][r];
    }
  }
  float acc[4] = {0.f,0.f,0.f,0.f};
  #pragma unroll
  for (int zc=0; zc<KSPLIT; ++zc){
    hf4 v = ((const hf4*)oall)[zc*(NE/4) + t];
    #pragma unroll
    for (int r=0;r<4;++r) acc[r] += az[zc][r]*(float)v[r];
  }
  #pragma unroll
  for (int r=0;r<4;++r)
    out[(size_t)(row0 + r)*D_ + vt*16 + l16] = acc[r]/den[r];
}

extern "C" void kernel_launch(void* const* d_in, const int* in_sizes, int n_in,
                              void* d_out, int out_size, void* d_ws, size_t ws_size,
                              hipStream_t stream) {
  const float* x    = (const float*)d_in[0];
  const int*   mask = (const int*)d_in[1];
  float*       out  = (float*)d_out;

  _Float16* x16  = (_Float16*)d_ws;
  _Float16* vtl  = x16 + NE;
  _Float16* oall = vtl + NE;                       // KSPLIT*NE fp16
  float*    mlm  = (float*)(oall + (size_t)KSPLIT*NE);
  float*    mll  = mlm + (size_t)KSPLIT*NROW;      // total ~51 MB

  prep_k   <<<dim3(D_/64, L_/64, B_), dim3(256), 0, stream>>>(x, x16, vtl);
  flash_k  <<<dim3(L_/128, B_, KSPLIT), dim3(256), 0, stream>>>(x16, vtl, mask, oall, mlm, mll);
  combine_k<<<dim3((int)(NE/4/256)), dim3(256), 0, stream>>>(out, oall, mlm, mll);
}